// Round 2
// baseline (1635.627 us; speedup 1.0000x reference)
//
#include <hip/hip_runtime.h>
#include <hip/hip_bf16.h>
#include <math.h>

typedef __hip_bfloat16 bf16;

#define L_SEQ 256
#define NB 4
#define EMB 768
#define DPOS 64
#define NH 12
#define DFF 3072
#define HD 64

// Load element i of an EXTERNAL tensor whose dtype is runtime-determined:
// f32 != 0 -> fp32, else bf16.
__device__ __forceinline__ float ldE(const void* p, size_t i, int f32) {
    return f32 ? ((const float*)p)[i]
               : __bfloat162float(((const bf16*)p)[i]);
}

// Detect input dtype. If src is fp32 read as 32-bit words, the LOW 16 bits are
// mantissa garbage -> interpreted as bf16, ~24% have exponent >= 0xC3 (|v|>2^68,
// inf, nan). If src is genuinely bf16 (values ~N(0,1)), exponent <= ~0x81 -> 0 hits.
__global__ void detect_kernel(const void* __restrict__ src, int* __restrict__ flagp) {
    __shared__ int cnt[256];
    int t = threadIdx.x;
    unsigned w = ((const unsigned*)src)[t];
    unsigned lo = w & 0xFFFFu;
    unsigned e = (lo >> 7) & 0xFFu;
    cnt[t] = (e >= 0xC3u) ? 1 : 0;
    __syncthreads();
    for (int off = 128; off; off >>= 1) {
        if (t < off) cnt[t] += cnt[t + off];
        __syncthreads();
    }
    if (t == 0) *flagp = (cnt[0] > 8) ? 1 : 0;
}

// C[M,OUT] = act( (A[M,K] @ W[OUT,K]^T + bias) * scale + residual )
// AMODE: 0 = A is internal fp32, 1 = A external (flag dtype), 2 = A internal bf16
// ACT:   0 none, 1 exact GELU
// RES:   0 none, 1 internal fp32 residual (residF), 2 external residual (residE)
// OUTB:  0 write fp32, 1 write bf16
template <int AMODE, int ACT, int RES, int OUTB>
__global__ void gemm_wt(const void* __restrict__ A, const void* __restrict__ W,
                        const void* __restrict__ bias,
                        const float* __restrict__ residF, const void* __restrict__ residE,
                        void* __restrict__ C, int M, int K, int OUT, float scale,
                        const int* __restrict__ flagp) {
    const int f32 = *flagp;
    __shared__ float As[32][33];
    __shared__ float Ws[32][33];
    int tx = threadIdx.x, ty = threadIdx.y;
    int tid = ty * 16 + tx;
    int bx = blockIdx.x, by = blockIdx.y;
    float acc00 = 0.f, acc01 = 0.f, acc10 = 0.f, acc11 = 0.f;
    for (int k0 = 0; k0 < K; k0 += 32) {
        #pragma unroll
        for (int it = 0; it < 4; ++it) {
            int l = tid + 256 * it;
            int r = l >> 5, c = l & 31;
            size_t ai = (size_t)(by * 32 + r) * K + k0 + c;
            if (AMODE == 0)      As[r][c] = ((const float*)A)[ai];
            else if (AMODE == 2) As[r][c] = __bfloat162float(((const bf16*)A)[ai]);
            else                 As[r][c] = ldE(A, ai, f32);
            Ws[r][c] = ldE(W, (size_t)(bx * 32 + r) * K + k0 + c, f32);
        }
        __syncthreads();
        #pragma unroll
        for (int kk = 0; kk < 32; ++kk) {
            float a0 = As[ty][kk], a1 = As[ty + 16][kk];
            float b0 = Ws[tx][kk], b1 = Ws[tx + 16][kk];
            acc00 += a0 * b0; acc01 += a0 * b1;
            acc10 += a1 * b0; acc11 += a1 * b1;
        }
        __syncthreads();
    }
    float accs[2][2] = {{acc00, acc01}, {acc10, acc11}};
    #pragma unroll
    for (int i = 0; i < 2; ++i)
        #pragma unroll
        for (int j = 0; j < 2; ++j) {
            int r = by * 32 + ty + i * 16;
            int o = bx * 32 + tx + j * 16;
            float v = (accs[i][j] + ldE(bias, o, f32)) * scale;
            size_t ci = (size_t)r * OUT + o;
            if (RES == 1) v += residF[ci];
            if (RES == 2) v += ldE(residE, ci, f32);
            if (ACT == 1) v = 0.5f * v * (1.0f + erff(v * 0.70710678118654752f));
            if (OUTB) ((bf16*)C)[ci] = __float2bfloat16(v);
            else      ((float*)C)[ci] = v;
        }
}

// qp[n,h,i,c] = sum_d q[i,n,h,d] * p_w[h*64+d, c];  qpb[n,h,i] = sum_d q * p_b
__global__ void qp_kernel(const float* __restrict__ qbuf, const void* __restrict__ p_w,
                          const void* __restrict__ p_b, float* __restrict__ qp,
                          float* __restrict__ qpb, const int* __restrict__ flagp) {
    const int f32 = *flagp;
    int blk = blockIdx.x;                // (n*NH + h)*L + i
    int i = blk % L_SEQ;
    int h = (blk / L_SEQ) % NH;
    int n = blk / (L_SEQ * NH);
    int t = threadIdx.x;                 // 0..63
    __shared__ float qs[64];
    qs[t] = qbuf[(size_t)(i * NB + n) * EMB + h * HD + t];
    __syncthreads();
    float acc = 0.f;
    #pragma unroll 8
    for (int d = 0; d < 64; ++d)
        acc += qs[d] * ldE(p_w, (size_t)(h * HD + d) * DPOS + t, f32);
    qp[(size_t)blk * 64 + t] = acc;
    float v = qs[t] * ldE(p_b, h * HD + t, f32);
    #pragma unroll
    for (int off = 32; off; off >>= 1) v += __shfl_down(v, off);
    if (t == 0) qpb[blk] = v;
}

// Fused scores + softmax + ctx: one block per (n,h,i), 256 threads.
__global__ void attn_kernel(const float* __restrict__ qbuf, const float* __restrict__ kbuf,
                            const float* __restrict__ vbuf, const void* __restrict__ pos,
                            const float* __restrict__ qp, const float* __restrict__ qpb,
                            float* __restrict__ ctx, const int* __restrict__ flagp) {
    const int f32 = *flagp;
    int blk = blockIdx.x;
    int i = blk % L_SEQ;
    int h = (blk / L_SEQ) % NH;
    int n = blk / (L_SEQ * NH);
    int j = threadIdx.x;                 // 0..255
    __shared__ float qs[64], qps[64];
    __shared__ float red[256], prob[256];
    __shared__ float part[4][64];
    if (j < 64) {
        qs[j] = qbuf[(size_t)(i * NB + n) * EMB + h * HD + j];
        qps[j] = qp[(size_t)blk * 64 + j];
    }
    __syncthreads();
    const float* krow = kbuf + (size_t)(j * NB + n) * EMB + h * HD;
    size_t pbase = ((size_t)(n * L_SEQ + i) * L_SEQ + j) * DPOS;
    float s = qpb[blk];
    #pragma unroll 8
    for (int d = 0; d < 64; ++d) s += qs[d] * krow[d];
    #pragma unroll 8
    for (int c = 0; c < 64; ++c) s += qps[c] * ldE(pos, pbase + c, f32);
    red[j] = s;
    __syncthreads();
    for (int off = 128; off; off >>= 1) {
        if (j < off) red[j] = fmaxf(red[j], red[j + off]);
        __syncthreads();
    }
    float mx = red[0];
    __syncthreads();
    float e = expf(s - mx);
    prob[j] = e;
    red[j] = e;
    __syncthreads();
    for (int off = 128; off; off >>= 1) {
        if (j < off) red[j] += red[j + off];
        __syncthreads();
    }
    float inv = 1.0f / red[0];
    // ctx: group g handles keys [g*64, g*64+64), lane d handles head dim d
    int g = j >> 6, d = j & 63;
    float p0 = 0.f;
    #pragma unroll 4
    for (int jj = g * 64; jj < g * 64 + 64; ++jj)
        p0 += prob[jj] * vbuf[(size_t)(jj * NB + n) * EMB + h * HD + d];
    part[g][d] = p0;
    __syncthreads();
    if (j < 64)
        ctx[(size_t)(i * NB + n) * EMB + h * HD + j] =
            (part[0][j] + part[1][j] + part[2][j] + part[3][j]) * inv;
}

// LayerNorm over rows of 768. FINAL: 0 -> write fp32 to outF; 1 -> write d_out
// with runtime dtype (flag).
template <int FINAL>
__global__ void ln_kernel(const float* __restrict__ X, const void* __restrict__ g,
                          const void* __restrict__ b, float* __restrict__ outF,
                          void* __restrict__ outAny, const int* __restrict__ flagp) {
    const int f32 = *flagp;
    int r = blockIdx.x;
    int t = threadIdx.x;                 // 0..255
    __shared__ float red[256];
    float x0 = X[(size_t)r * EMB + t];
    float x1 = X[(size_t)r * EMB + t + 256];
    float x2 = X[(size_t)r * EMB + t + 512];
    red[t] = x0 + x1 + x2;
    __syncthreads();
    for (int off = 128; off; off >>= 1) {
        if (t < off) red[t] += red[t + off];
        __syncthreads();
    }
    float mean = red[0] * (1.0f / EMB);
    __syncthreads();
    float d0 = x0 - mean, d1 = x1 - mean, d2 = x2 - mean;
    red[t] = d0 * d0 + d1 * d1 + d2 * d2;
    __syncthreads();
    for (int off = 128; off; off >>= 1) {
        if (t < off) red[t] += red[t + off];
        __syncthreads();
    }
    float rstd = rsqrtf(red[0] * (1.0f / EMB) + 1e-5f);
    float vs[3] = {d0, d1, d2};
    #pragma unroll
    for (int p = 0; p < 3; ++p) {
        int e = t + p * 256;
        float v = vs[p] * rstd * ldE(g, e, f32) + ldE(b, e, f32);
        size_t oi = (size_t)r * EMB + e;
        if (FINAL) {
            if (f32) ((float*)outAny)[oi] = v;
            else     ((bf16*)outAny)[oi] = __float2bfloat16(v);
        } else {
            outF[oi] = v;
        }
    }
}

extern "C" void kernel_launch(void* const* d_in, const int* in_sizes, int n_in,
                              void* d_out, int out_size, void* d_ws, size_t ws_size,
                              hipStream_t stream) {
    const void* src    = d_in[0];
    const void* pos    = d_in[1];
    const void* q_w    = d_in[2];
    const void* q_b    = d_in[3];
    const void* k_w    = d_in[4];
    const void* k_b    = d_in[5];
    const void* v_w    = d_in[6];
    const void* v_b    = d_in[7];
    const void* p_w    = d_in[8];
    const void* p_b    = d_in[9];
    const void* out_w  = d_in[10];
    const void* out_b  = d_in[11];
    const void* lin1_w = d_in[12];
    const void* lin1_b = d_in[13];
    const void* lin2_w = d_in[14];
    const void* lin2_b = d_in[15];
    const void* n1_g   = d_in[16];
    const void* n1_b   = d_in[17];
    const void* n2_g   = d_in[18];
    const void* n2_b   = d_in[19];

    const int M = L_SEQ * NB;            // 1024
    float* f = (float*)d_ws;
    // Overlaid layout (float offsets). Lifetimes:
    //   slot0: qbuf (dead after attn) -> y (out-proj, dead after ln1) -> y2 (lin2)
    //   slot1: kbuf (dead after attn) -> x1 (ln1 out, read by lin1+lin2)
    //   slot2: vbuf (dead after attn)
    //   slot3: qp (dead after attn); slot4: qpb; slot5: ctx (dead after out-proj)
    //   ff (bf16, 3145728 elems = 1572864 float-slots) overlays slot3..slot5 tail
    float* qbuf = f;                     // 786432
    float* kbuf = f + 786432;            // 786432
    float* vbuf = f + 1572864;           // 786432
    float* qp   = f + 2359296;           // 786432
    float* qpb  = f + 3145728;           // 12288
    float* ctx  = f + 3158016;           // 786432
    bf16*  ff   = (bf16*)(f + 2359296);  // 3145728 bf16 = 1572864 floats (overlay)
    float* y    = qbuf;                  // overlay
    float* x1   = kbuf;                  // overlay
    float* y2   = qbuf;                  // overlay
    int*   flagp = (int*)(f + 3944448);  // total ws used: ~15.8 MB

    dim3 thr(16, 16);
    const float scaling = 0.125f;        // 64^-0.5

    detect_kernel<<<1, 256, 0, stream>>>(src, flagp);

    // Q/K/V projections
    gemm_wt<1, 0, 0, 0><<<dim3(EMB / 32, M / 32), thr, 0, stream>>>(
        src, q_w, q_b, nullptr, nullptr, qbuf, M, EMB, EMB, scaling, flagp);
    gemm_wt<1, 0, 0, 0><<<dim3(EMB / 32, M / 32), thr, 0, stream>>>(
        src, k_w, k_b, nullptr, nullptr, kbuf, M, EMB, EMB, 1.0f, flagp);
    gemm_wt<1, 0, 0, 0><<<dim3(EMB / 32, M / 32), thr, 0, stream>>>(
        src, v_w, v_b, nullptr, nullptr, vbuf, M, EMB, EMB, 1.0f, flagp);

    // qp = q @ p_w (per head), qpb = q . p_b
    qp_kernel<<<NB * NH * L_SEQ, 64, 0, stream>>>(qbuf, p_w, p_b, qp, qpb, flagp);

    // fused scores + softmax + ctx
    attn_kernel<<<NB * NH * L_SEQ, 256, 0, stream>>>(qbuf, kbuf, vbuf, pos, qp, qpb,
                                                     ctx, flagp);

    // out projection + residual(src) -> y ; LN1 -> x1
    gemm_wt<0, 0, 2, 0><<<dim3(EMB / 32, M / 32), thr, 0, stream>>>(
        ctx, out_w, out_b, nullptr, src, y, M, EMB, EMB, 1.0f, flagp);
    ln_kernel<0><<<M, 256, 0, stream>>>(y, n1_g, n1_b, x1, nullptr, flagp);

    // FF: lin1 + GELU -> ff (bf16), lin2 + residual(x1) -> y2
    gemm_wt<0, 1, 0, 1><<<dim3(DFF / 32, M / 32), thr, 0, stream>>>(
        x1, lin1_w, lin1_b, nullptr, nullptr, ff, M, EMB, DFF, 1.0f, flagp);
    gemm_wt<2, 0, 1, 0><<<dim3(EMB / 32, M / 32), thr, 0, stream>>>(
        ff, lin2_w, lin2_b, x1, nullptr, y2, M, DFF, EMB, 1.0f, flagp);
    ln_kernel<1><<<M, 256, 0, stream>>>(y2, n2_g, n2_b, nullptr, d_out, flagp);
}